// Round 11
// baseline (276.404 us; speedup 1.0000x reference)
//
#include <hip/hip_runtime.h>
#include <hip/hip_bf16.h>

#define B_ 4
#define C_ 256
#define L_ 4096
#define G_ 32
#define KVS_ 4

typedef __attribute__((ext_vector_type(8))) short bf16x8;
typedef __attribute__((ext_vector_type(4))) float f32x4;
typedef __attribute__((ext_vector_type(16))) float f32x16;
typedef __attribute__((ext_vector_type(4))) unsigned short us4;
typedef __attribute__((ext_vector_type(8))) unsigned short us8;
typedef __attribute__((ext_vector_type(4))) unsigned int u32x4;

__device__ __forceinline__ unsigned short f2bf(float f) {
  unsigned u = __builtin_bit_cast(unsigned, f);
  u += 0x7fffu + ((u >> 16) & 1u);
  return (unsigned short)(u >> 16);
}
__device__ __forceinline__ float bf2f(unsigned short s) {
  return __builtin_bit_cast(float, (unsigned)s << 16);
}

__device__ __forceinline__ void async_copy16(const void* g, void* l) {
  __builtin_amdgcn_global_load_lds((const __attribute__((address_space(1))) void*)g,
                                   (__attribute__((address_space(3))) void*)l, 16, 0, 0);
}

// ---------------- weights fp32 -> bf16 (all 4 in one launch) ----------------
__global__ void wcvt_kernel(const float* __restrict__ qw, const float* __restrict__ kw,
                            const float* __restrict__ vw, const float* __restrict__ pw,
                            unsigned short* __restrict__ dst) {
  int m = blockIdx.x >> 6;
  const float* src = (m == 0) ? qw : ((m == 1) ? kw : ((m == 2) ? vw : pw));
  int i = ((blockIdx.x & 63) * 256 + threadIdx.x) * 4;
  float4 v = *(const float4*)(src + i);
  us4 o;
  o[0] = f2bf(v.x); o[1] = f2bf(v.y); o[2] = f2bf(v.z); o[3] = f2bf(v.w);
  *(us4*)(dst + m * C_ * C_ + i) = o;
}

// ---------------- fused GroupNorm (stats + apply) -> xn_t [b][l][c] bf16 ----------------
__global__ __launch_bounds__(256) void gn_kernel(const float* __restrict__ x,
                                                 const float* __restrict__ gw,
                                                 const float* __restrict__ gb,
                                                 unsigned short* __restrict__ xn_t) {
  int bg = blockIdx.x;                       // 128 = b*32+g
  int b = bg >> 5, g = bg & 31;
  const float* xp = x + (size_t)bg * 8 * L_;
  float s = 0.f, ss = 0.f;
  for (int i = threadIdx.x * 4; i < 8 * L_; i += 1024) {
    float4 v = *(const float4*)(xp + i);
    s += v.x + v.y + v.z + v.w;
    ss += v.x * v.x + v.y * v.y + v.z * v.z + v.w * v.w;
  }
#pragma unroll
  for (int m = 1; m < 64; m <<= 1) { s += __shfl_xor(s, m); ss += __shfl_xor(ss, m); }
  __shared__ float red[8];
  int w = threadIdx.x >> 6;
  if ((threadIdx.x & 63) == 0) { red[w] = s; red[4 + w] = ss; }
  __syncthreads();
  s = red[0] + red[1] + red[2] + red[3];
  ss = red[4] + red[5] + red[6] + red[7];
  const float inv_n = 1.f / (8.f * L_);
  float mean = s * inv_n;
  float rstd = rsqrtf(ss * inv_n - mean * mean + 1e-6f);

  float sw[8], sb[8];
#pragma unroll
  for (int j = 0; j < 8; ++j) {
    int c = g * 8 + j;
    sw[j] = gw[c] * rstd;
    sb[j] = gb[c] - mean * sw[j];
  }
#pragma unroll 1
  for (int lc = 0; lc < 4; ++lc) {
    int l = lc * 1024 + threadIdx.x * 4;
    float res[4][8];
#pragma unroll
    for (int j = 0; j < 8; ++j) {
      float4 v = *(const float4*)(x + ((size_t)b * C_ + g * 8 + j) * L_ + l);
      res[0][j] = v.x * sw[j] + sb[j]; res[1][j] = v.y * sw[j] + sb[j];
      res[2][j] = v.z * sw[j] + sb[j]; res[3][j] = v.w * sw[j] + sb[j];
    }
#pragma unroll
    for (int i = 0; i < 4; ++i) {
      us8 o;
#pragma unroll
      for (int j = 0; j < 8; ++j) o[j] = f2bf(res[i][j]);
      *(us8*)(xn_t + ((size_t)b * L_ + l + i) * C_ + g * 8) = o;
    }
  }
}

// ---------------- fused QKV GEMM (q pre-scaled by C^-0.5 * log2e) ----------------
__global__ __launch_bounds__(256) void qkv_gemm_kernel(
    const unsigned short* __restrict__ wq, const unsigned short* __restrict__ wk,
    const unsigned short* __restrict__ wv, const float* __restrict__ qbias,
    const float* __restrict__ kbias, const float* __restrict__ vbias,
    const unsigned short* __restrict__ xn, unsigned short* __restrict__ qt,
    unsigned short* __restrict__ kt, unsigned short* __restrict__ vt) {
  int id = blockIdx.x;                 // 1024 = b(4) x mt(4) x nt(64)
  int nt = id & 63, mt = (id >> 6) & 3, b = (id >> 8) & 3;
  int lane = threadIdx.x & 63, wid = threadIdx.x >> 6;
  int ln = lane & 15, lq = lane >> 4;
  int m0 = mt * 64 + wid * 16;
  int n0 = nt * 64;
  const unsigned short* xb = xn + (size_t)b * L_ * C_;
  bf16x8 aq[8], ak[8], av[8];
  const unsigned short* arow = wq + (m0 + ln) * C_ + lq * 8;
#pragma unroll
  for (int ks = 0; ks < 8; ++ks) aq[ks] = *(const bf16x8*)(arow + ks * 32);
  arow = wk + (m0 + ln) * C_ + lq * 8;
#pragma unroll
  for (int ks = 0; ks < 8; ++ks) ak[ks] = *(const bf16x8*)(arow + ks * 32);
  arow = wv + (m0 + ln) * C_ + lq * 8;
#pragma unroll
  for (int ks = 0; ks < 8; ++ks) av[ks] = *(const bf16x8*)(arow + ks * 32);

  int o0 = m0 + lq * 4;
  float bq[4], bk[4], bv[4];
#pragma unroll
  for (int r = 0; r < 4; ++r) { bq[r] = qbias[o0 + r]; bk[r] = kbias[o0 + r]; bv[r] = vbias[o0 + r]; }
  unsigned short* qd = qt + (size_t)b * L_ * C_;
  unsigned short* kd = kt + (size_t)b * L_ * C_;
  unsigned short* vd = vt + (size_t)b * C_ * L_;
  const float QSCALE = 0.0625f * 1.44269504f;   // C^-0.5 * log2e folded into q

#pragma unroll
  for (int t = 0; t < 4; ++t) {
    f32x4 cq = {0.f, 0.f, 0.f, 0.f}, ck = cq, cv = cq;
    const unsigned short* brow = xb + (size_t)(n0 + 16 * t + ln) * C_ + lq * 8;
#pragma unroll
    for (int ks = 0; ks < 8; ++ks) {
      bf16x8 bf = *(const bf16x8*)(brow + ks * 32);
      cq = __builtin_amdgcn_mfma_f32_16x16x32_bf16(aq[ks], bf, cq, 0, 0, 0);
      ck = __builtin_amdgcn_mfma_f32_16x16x32_bf16(ak[ks], bf, ck, 0, 0, 0);
      cv = __builtin_amdgcn_mfma_f32_16x16x32_bf16(av[ks], bf, cv, 0, 0, 0);
    }
    int l = n0 + 16 * t + ln;
    us4 pk;
#pragma unroll
    for (int r = 0; r < 4; ++r) pk[r] = f2bf((cq[r] + bq[r]) * QSCALE);
    *(us4*)(qd + (size_t)l * C_ + o0) = pk;
#pragma unroll
    for (int r = 0; r < 4; ++r) pk[r] = f2bf(ck[r] + bk[r]);
    *(us4*)(kd + (size_t)l * C_ + o0) = pk;
#pragma unroll
    for (int r = 0; r < 4; ++r) vd[(size_t)(o0 + r) * L_ + l] = f2bf(cv[r] + bv[r]);
  }
}

// ---------------- Flash attention: 8-wave, 64-key phases (2 halves), K+V dbuf 128KB ----------
// q,k: [b][l][c] bf16 (q pre-scaled, log2 domain); v: [b][c][l] bf16.
// Per 64-key phase: 1 vmcnt + 2 barriers (half the sync of the 32-key schedule); halves
// computed sequentially reusing the same transient registers -> VGPR unchanged (~128).
__global__ __launch_bounds__(512) void attn_kernel(
    const unsigned short* __restrict__ qt, const unsigned short* __restrict__ kt,
    const unsigned short* __restrict__ vt, unsigned short* __restrict__ po,
    float2* __restrict__ ml) {
  __shared__ __attribute__((aligned(16))) char Kl[2][32768];  // 64 keys x 512B, src XOR (row&31)<<4
  __shared__ __attribute__((aligned(16))) char Vl[2][32768];  // 256 c x 128B, src XOR ((c>>1)&3)<<4 ^ (c&1)<<6

  // XCD-chunked: 32 consecutive idx per XCD -> 2 (b,s) groups, KV slice ~2MB L2-resident
  int idx = (blockIdx.x & 7) * 32 + (blockIdx.x >> 3);
  int g = idx >> 4;                      // 0..15 = b*4+s
  int qtile = idx & 15;
  int b = g >> 2, s = g & 3;
  int jbase = s * (L_ / KVS_);
  const int NP = (L_ / KVS_) / 64;       // 16 phases of 64 keys

  int tid = threadIdx.x;
  int lane = tid & 63, wid = tid >> 6;
  int lq = lane & 31;                    // q-col / key-row / c-row
  int lk = lane >> 5;
  int q0 = qtile * 256 + wid * 32;

  const unsigned short* qb_ = qt + (size_t)b * L_ * C_;
  const unsigned short* kb_ = kt + (size_t)b * L_ * C_;
  const unsigned short* vb_ = vt + (size_t)b * C_ * L_;

  // staging (512 thr): 64-key tile = K 32KB (4x16B/thread) + V 32KB (4x16B/thread)
  auto stage = [&](int j0, int bs) {
#pragma unroll
    for (int r = 0; r < 4; ++r) {
      int addr = r * 8192 + tid * 16;
      int row = addr >> 9, colb = addr & 511;
      async_copy16((const char*)kb_ + (size_t)(j0 + row) * 512 + (colb ^ ((row & 31) << 4)),
                   Kl[bs] + addr);
    }
#pragma unroll
    for (int r = 0; r < 4; ++r) {
      int addr = r * 8192 + tid * 16;
      int c = addr >> 7, colb = addr & 127;
      int swz = (((c >> 1) & 3) << 4) ^ ((c & 1) << 6);
      async_copy16((const char*)vb_ + (size_t)c * (L_ * 2) + (size_t)j0 * 2 + (colb ^ swz),
                   Vl[bs] + addr);
    }
  };

  // Q B-fragments: qf[kc] = Q[q0+lq][kc*16 + lk*8 .. +7]
  bf16x8 qf[16];
  const unsigned short* qrow = qb_ + (size_t)(q0 + lq) * C_ + lk * 8;
#pragma unroll
  for (int kc = 0; kc < 16; ++kc) qf[kc] = *(const bf16x8*)(qrow + kc * 16);

  // prologue: tiles 0,1 staged (16 loads outstanding)
  stage(jbase, 0);
  stage(jbase + 64, 1);

  f32x16 oacc[8];
#pragma unroll
  for (int ct = 0; ct < 8; ++ct)
#pragma unroll
    for (int i = 0; i < 16; ++i) oacc[ct][i] = 0.f;

  float m_run = -3e38f, l_run = 0.f;     // log2 domain
  const int kswz = lq << 4;              // full-row spread (2-way max on ds_read_b128)
  const int vswz = (((lq >> 1) & 3) << 4) ^ ((lq & 1) << 6);

  // one 32-key half: QK -> softmax -> pack -> PV
  auto half = [&](const char* Kb, const char* Vb, int h) {
    const char* Kh = Kb + h * 16384;     // rows h*32..h*32+31
    // ---- QK: S^T = K · Q^T (2 parallel chains); S in log2 units ----
    f32x16 sa, sb;
#pragma unroll
    for (int i = 0; i < 16; ++i) { sa[i] = 0.f; sb[i] = 0.f; }
    __builtin_amdgcn_s_setprio(1);
#pragma unroll
    for (int kc = 0; kc < 16; kc += 2) {
      bf16x8 kf0 = *(const bf16x8*)(Kh + lq * 512 + ((kc * 32 + lk * 16) ^ kswz));
      sa = __builtin_amdgcn_mfma_f32_32x32x16_bf16(kf0, qf[kc], sa, 0, 0, 0);
      bf16x8 kf1 = *(const bf16x8*)(Kh + lq * 512 + (((kc + 1) * 32 + lk * 16) ^ kswz));
      sb = __builtin_amdgcn_mfma_f32_32x32x16_bf16(kf1, qf[kc + 1], sb, 0, 0, 0);
    }
    __builtin_amdgcn_s_setprio(0);
    f32x16 sacc = sa + sb;

    // ---- online softmax, in-register, log2 domain ----
    float pm = sacc[0];
#pragma unroll
    for (int i = 1; i < 16; ++i) pm = fmaxf(pm, sacc[i]);
    pm = fmaxf(pm, __shfl_xor(pm, 32));
    if (__any(pm > m_run + 8.0f)) {      // defer-max (T13)
      float mn = fmaxf(m_run, pm);
      float al = exp2f(m_run - mn);
      l_run *= al;
#pragma unroll
      for (int ct = 0; ct < 8; ++ct)
#pragma unroll
        for (int i = 0; i < 16; ++i) oacc[ct][i] *= al;
      m_run = mn;
    }
    float p[16];
    float ls = 0.f;
#pragma unroll
    for (int i = 0; i < 16; ++i) {
      p[i] = exp2f(sacc[i] - m_run);
      ls += p[i];
    }
    ls += __shfl_xor(ls, 32);
    l_run += ls;

    // ---- pack P -> bf16 B-frags via cvt_pk + permlane32_swap (T12) ----
    unsigned w[8];
#pragma unroll
    for (int i = 0; i < 8; ++i)
      asm("v_cvt_pk_bf16_f32 %0, %1, %2" : "=v"(w[i]) : "v"(p[2 * i]), "v"(p[2 * i + 1]));
    asm volatile("v_permlane32_swap_b32 %0, %1" : "+v"(w[0]), "+v"(w[2]));
    asm volatile("v_permlane32_swap_b32 %0, %1" : "+v"(w[1]), "+v"(w[3]));
    asm volatile("v_permlane32_swap_b32 %0, %1" : "+v"(w[4]), "+v"(w[6]));
    asm volatile("v_permlane32_swap_b32 %0, %1" : "+v"(w[5]), "+v"(w[7]));
    u32x4 t1 = {w[0], w[1], w[2], w[3]};
    u32x4 t2 = {w[4], w[5], w[6], w[7]};
    bf16x8 pb1 = __builtin_bit_cast(bf16x8, t1);
    bf16x8 pb2 = __builtin_bit_cast(bf16x8, t2);

    // ---- PV: O^T += V^T · P^T, V from LDS (keys h*32 .. h*32+31) ----
    __builtin_amdgcn_s_setprio(1);
#pragma unroll
    for (int ct = 0; ct < 8; ++ct) {
      int vr = ct * 32 + lq;
      bf16x8 av0 = *(const bf16x8*)(Vb + vr * 128 + ((h * 64 + lk * 16) ^ vswz));
      oacc[ct] = __builtin_amdgcn_mfma_f32_32x32x16_bf16(av0, pb1, oacc[ct], 0, 0, 0);
      bf16x8 av1 = *(const bf16x8*)(Vb + vr * 128 + ((h * 64 + 32 + lk * 16) ^ vswz));
      oacc[ct] = __builtin_amdgcn_mfma_f32_32x32x16_bf16(av1, pb2, oacc[ct], 0, 0, 0);
    }
    __builtin_amdgcn_s_setprio(0);
  };

#pragma unroll 1
  for (int p = 0; p < NP; ++p) {
    const char* Kb = Kl[p & 1];
    const char* Vb = Vl[p & 1];

    // tile p's 8 loads are the oldest -> drained; tile p+1's 8 stay in flight
    asm volatile("s_waitcnt vmcnt(8)" ::: "memory");
    __builtin_amdgcn_sched_barrier(0);
    __builtin_amdgcn_s_barrier();
    __builtin_amdgcn_sched_barrier(0);

    half(Kb, Vb, 0);
    __builtin_amdgcn_sched_barrier(0);   // pin register pressure between halves
    half(Kb, Vb, 1);

    __builtin_amdgcn_sched_barrier(0);
    __builtin_amdgcn_s_barrier();        // all reads of buf p&1 done
    __builtin_amdgcn_sched_barrier(0);
    stage(jbase + ((p + 2) & (NP - 1)) * 64, p & 1);  // wrap keeps vmcnt uniform
  }

  asm volatile("s_waitcnt vmcnt(0)" ::: "memory");  // drain wrap staging

  // ---- epilogue: unnormalized O partial + (m,l) (log2 domain) ----
  unsigned short* pob = po + ((size_t)g * L_ + q0 + lq) * C_;
#pragma unroll
  for (int ct = 0; ct < 8; ++ct) {
#pragma unroll
    for (int e = 0; e < 4; ++e) {
      us4 pk;
#pragma unroll
      for (int r = 0; r < 4; ++r) pk[r] = f2bf(oacc[ct][4 * e + r]);
      *(us4*)(pob + ct * 32 + 8 * e + 4 * lk) = pk;
    }
  }
  if (lane < 32)
    ml[(size_t)g * L_ + q0 + lq] = make_float2(m_run, l_run);
}

// ---------------- combine partials -> ot [b][l][c] bf16 (log2 domain m) ----------------
__global__ void combine_kernel(const unsigned short* __restrict__ po,
                               const float2* __restrict__ ml,
                               unsigned short* __restrict__ ot) {
  int tid = threadIdx.x;
  int row = blockIdx.x * 4 + (tid >> 6);   // b*L + l
  int b = row >> 12;
  int l = row & (L_ - 1);
  int lane = tid & 63;
  float2 mv[KVS_];
  float M = -3e38f;
#pragma unroll
  for (int s = 0; s < KVS_; ++s) {
    mv[s] = ml[(size_t)(b * KVS_ + s) * L_ + l];
    M = fmaxf(M, mv[s].x);
  }
  float acc[4] = {0.f, 0.f, 0.f, 0.f};
  float denom = 0.f;
#pragma unroll
  for (int s = 0; s < KVS_; ++s) {
    float w = exp2f(mv[s].x - M);
    denom += w * mv[s].y;
    us4 o = *(const us4*)(po + ((size_t)(b * KVS_ + s) * L_ + l) * C_ + lane * 4);
#pragma unroll
    for (int j = 0; j < 4; ++j) acc[j] += w * bf2f(o[j]);
  }
  float inv = 1.f / denom;
  us4 o;
#pragma unroll
  for (int j = 0; j < 4; ++j) o[j] = f2bf(acc[j] * inv);
  *(us4*)(ot + (size_t)row * C_ + lane * 4) = o;
}

// ---------------- proj GEMM + bias + residual (fp32 out) ----------------
__global__ __launch_bounds__(256) void proj_kernel(
    const unsigned short* __restrict__ wp, const float* __restrict__ pbias,
    const unsigned short* __restrict__ ot, const float* __restrict__ x,
    float* __restrict__ out) {
  int id = blockIdx.x;
  int nt = id & 63, mt = (id >> 6) & 3, b = id >> 8;
  int lane = threadIdx.x & 63, wid = threadIdx.x >> 6;
  int ln = lane & 15, lq = lane >> 4;
  int m0 = mt * 64 + wid * 16;
  int n0 = nt * 64;
  const unsigned short* ob = ot + (size_t)b * L_ * C_;
  bf16x8 a[8];
  const unsigned short* arow = wp + (m0 + ln) * C_ + lq * 8;
#pragma unroll
  for (int ks = 0; ks < 8; ++ks) a[ks] = *(const bf16x8*)(arow + ks * 32);
  f32x4 acc[4];
#pragma unroll
  for (int t = 0; t < 4; ++t) {
    f32x4 c = {0.f, 0.f, 0.f, 0.f};
    const unsigned short* brow = ob + (size_t)(n0 + 16 * t + ln) * C_ + lq * 8;
#pragma unroll
    for (int ks = 0; ks < 8; ++ks) {
      bf16x8 bf = *(const bf16x8*)(brow + ks * 32);
      c = __builtin_amdgcn_mfma_f32_16x16x32_bf16(a[ks], bf, c, 0, 0, 0);
    }
    acc[t] = c;
  }
  int o0 = m0 + lq * 4;
#pragma unroll
  for (int r = 0; r < 4; ++r) {
    float bvr = pbias[o0 + r];
    const float* xrow = x + ((size_t)b * C_ + o0 + r) * L_;
    float* orow = out + ((size_t)b * C_ + o0 + r) * L_;
#pragma unroll
    for (int t = 0; t < 4; ++t) {
      int l = n0 + 16 * t + ln;
      orow[l] = xrow[l] + acc[t][r] + bvr;
    }
  }
}

extern "C" void kernel_launch(void* const* d_in, const int* in_sizes, int n_in,
                              void* d_out, int out_size, void* d_ws, size_t ws_size,
                              hipStream_t stream) {
  const float* x   = (const float*)d_in[0];
  const float* gnw = (const float*)d_in[1];
  const float* gnb = (const float*)d_in[2];
  const float* qw  = (const float*)d_in[3];
  const float* qb  = (const float*)d_in[4];
  const float* kw  = (const float*)d_in[5];
  const float* kb  = (const float*)d_in[6];
  const float* vw  = (const float*)d_in[7];
  const float* vb  = (const float*)d_in[8];
  const float* pw  = (const float*)d_in[9];
  const float* pb  = (const float*)d_in[10];
  float* out = (float*)d_out;

  unsigned short* ws = (unsigned short*)d_ws;
  const size_t SZ = (size_t)B_ * L_ * C_;
  unsigned short* xn_t = ws;            // [b][l][c] bf16
  unsigned short* qt   = xn_t + SZ;     // [b][l][c] (pre-scaled, log2 domain)
  unsigned short* kt   = qt + SZ;       // [b][l][c]
  unsigned short* vt   = kt + SZ;       // [b][c][l]
  unsigned short* ot   = vt + SZ;       // [b][l][c]
  unsigned short* wb   = ot + SZ;       // 4 x [C][C] bf16 (q,k,v,p)
  unsigned short* po   = wb + 4 * C_ * C_;                   // [B*KVS][L][C]
  float2* ml = (float2*)(po + (size_t)KVS_ * SZ);            // [B*KVS][L]

  wcvt_kernel<<<256, 256, 0, stream>>>(qw, kw, vw, pw, wb);
  gn_kernel<<<B_ * G_, 256, 0, stream>>>(x, gnw, gnb, xn_t);
  qkv_gemm_kernel<<<1024, 256, 0, stream>>>(wb, wb + C_ * C_, wb + 2 * C_ * C_,
                                            qb, kb, vb, xn_t, qt, kt, vt);
  attn_kernel<<<256, 512, 0, stream>>>(qt, kt, vt, po, ml);
  combine_kernel<<<B_ * L_ / 4, 256, 0, stream>>>(po, ml, ot);
  proj_kernel<<<1024, 256, 0, stream>>>(wb + 3 * C_ * C_, pb, ot, x, out);
}

// Round 12
// 207.504 us; speedup vs baseline: 1.3320x; 1.3320x over previous
//
#include <hip/hip_runtime.h>
#include <hip/hip_bf16.h>

#define B_ 4
#define C_ 256
#define L_ 4096
#define G_ 32
#define KVS_ 4

typedef __attribute__((ext_vector_type(8))) short bf16x8;
typedef __attribute__((ext_vector_type(4))) float f32x4;
typedef __attribute__((ext_vector_type(16))) float f32x16;
typedef __attribute__((ext_vector_type(4))) unsigned short us4;
typedef __attribute__((ext_vector_type(8))) unsigned short us8;
typedef __attribute__((ext_vector_type(4))) unsigned int u32x4;

__device__ __forceinline__ unsigned short f2bf(float f) {
  unsigned u = __builtin_bit_cast(unsigned, f);
  u += 0x7fffu + ((u >> 16) & 1u);
  return (unsigned short)(u >> 16);
}
__device__ __forceinline__ float bf2f(unsigned short s) {
  return __builtin_bit_cast(float, (unsigned)s << 16);
}

__device__ __forceinline__ void async_copy16(const void* g, void* l) {
  __builtin_amdgcn_global_load_lds((const __attribute__((address_space(1))) void*)g,
                                   (__attribute__((address_space(3))) void*)l, 16, 0, 0);
}

// ---------------- fused GroupNorm (blocks 0..127) + weight cvt (blocks 128..383) ----------------
__global__ __launch_bounds__(256) void gn_wcvt_kernel(
    const float* __restrict__ x, const float* __restrict__ gw, const float* __restrict__ gb,
    unsigned short* __restrict__ xn_t,
    const float* __restrict__ qw, const float* __restrict__ kw,
    const float* __restrict__ vw, const float* __restrict__ pw,
    unsigned short* __restrict__ wdst) {
  __shared__ float red[8];
  if (blockIdx.x >= 128) {
    // ---- weight fp32 -> bf16 ----
    int id = blockIdx.x - 128;
    int m = id >> 6;
    const float* src = (m == 0) ? qw : ((m == 1) ? kw : ((m == 2) ? vw : pw));
    int i = ((id & 63) * 256 + threadIdx.x) * 4;
    float4 v = *(const float4*)(src + i);
    us4 o;
    o[0] = f2bf(v.x); o[1] = f2bf(v.y); o[2] = f2bf(v.z); o[3] = f2bf(v.w);
    *(us4*)(wdst + m * C_ * C_ + i) = o;
    return;
  }
  int bg = blockIdx.x;                       // 128 = b*32+g
  int b = bg >> 5, g = bg & 31;
  const float* xp = x + (size_t)bg * 8 * L_;
  float s = 0.f, ss = 0.f;
  for (int i = threadIdx.x * 4; i < 8 * L_; i += 1024) {
    float4 v = *(const float4*)(xp + i);
    s += v.x + v.y + v.z + v.w;
    ss += v.x * v.x + v.y * v.y + v.z * v.z + v.w * v.w;
  }
#pragma unroll
  for (int m = 1; m < 64; m <<= 1) { s += __shfl_xor(s, m); ss += __shfl_xor(ss, m); }
  int w = threadIdx.x >> 6;
  if ((threadIdx.x & 63) == 0) { red[w] = s; red[4 + w] = ss; }
  __syncthreads();
  s = red[0] + red[1] + red[2] + red[3];
  ss = red[4] + red[5] + red[6] + red[7];
  const float inv_n = 1.f / (8.f * L_);
  float mean = s * inv_n;
  float rstd = rsqrtf(ss * inv_n - mean * mean + 1e-6f);

  float sw[8], sb[8];
#pragma unroll
  for (int j = 0; j < 8; ++j) {
    int c = g * 8 + j;
    sw[j] = gw[c] * rstd;
    sb[j] = gb[c] - mean * sw[j];
  }
#pragma unroll 1
  for (int lc = 0; lc < 4; ++lc) {
    int l = lc * 1024 + threadIdx.x * 4;
    float res[4][8];
#pragma unroll
    for (int j = 0; j < 8; ++j) {
      float4 v = *(const float4*)(x + ((size_t)b * C_ + g * 8 + j) * L_ + l);
      res[0][j] = v.x * sw[j] + sb[j]; res[1][j] = v.y * sw[j] + sb[j];
      res[2][j] = v.z * sw[j] + sb[j]; res[3][j] = v.w * sw[j] + sb[j];
    }
#pragma unroll
    for (int i = 0; i < 4; ++i) {
      us8 o;
#pragma unroll
      for (int j = 0; j < 8; ++j) o[j] = f2bf(res[i][j]);
      *(us8*)(xn_t + ((size_t)b * L_ + l + i) * C_ + g * 8) = o;
    }
  }
}

// ---------------- fused QKV GEMM (q pre-scaled by C^-0.5 * log2e) ----------------
__global__ __launch_bounds__(256) void qkv_gemm_kernel(
    const unsigned short* __restrict__ wq, const unsigned short* __restrict__ wk,
    const unsigned short* __restrict__ wv, const float* __restrict__ qbias,
    const float* __restrict__ kbias, const float* __restrict__ vbias,
    const unsigned short* __restrict__ xn, unsigned short* __restrict__ qt,
    unsigned short* __restrict__ kt, unsigned short* __restrict__ vt) {
  int id = blockIdx.x;                 // 1024 = b(4) x mt(4) x nt(64)
  int nt = id & 63, mt = (id >> 6) & 3, b = (id >> 8) & 3;
  int lane = threadIdx.x & 63, wid = threadIdx.x >> 6;
  int ln = lane & 15, lq = lane >> 4;
  int m0 = mt * 64 + wid * 16;
  int n0 = nt * 64;
  const unsigned short* xb = xn + (size_t)b * L_ * C_;
  bf16x8 aq[8], ak[8], av[8];
  const unsigned short* arow = wq + (m0 + ln) * C_ + lq * 8;
#pragma unroll
  for (int ks = 0; ks < 8; ++ks) aq[ks] = *(const bf16x8*)(arow + ks * 32);
  arow = wk + (m0 + ln) * C_ + lq * 8;
#pragma unroll
  for (int ks = 0; ks < 8; ++ks) ak[ks] = *(const bf16x8*)(arow + ks * 32);
  arow = wv + (m0 + ln) * C_ + lq * 8;
#pragma unroll
  for (int ks = 0; ks < 8; ++ks) av[ks] = *(const bf16x8*)(arow + ks * 32);

  int o0 = m0 + lq * 4;
  float bq[4], bk[4], bv[4];
#pragma unroll
  for (int r = 0; r < 4; ++r) { bq[r] = qbias[o0 + r]; bk[r] = kbias[o0 + r]; bv[r] = vbias[o0 + r]; }
  unsigned short* qd = qt + (size_t)b * L_ * C_;
  unsigned short* kd = kt + (size_t)b * L_ * C_;
  unsigned short* vd = vt + (size_t)b * C_ * L_;
  const float QSCALE = 0.0625f * 1.44269504f;   // C^-0.5 * log2e folded into q

#pragma unroll
  for (int t = 0; t < 4; ++t) {
    f32x4 cq = {0.f, 0.f, 0.f, 0.f}, ck = cq, cv = cq;
    const unsigned short* brow = xb + (size_t)(n0 + 16 * t + ln) * C_ + lq * 8;
#pragma unroll
    for (int ks = 0; ks < 8; ++ks) {
      bf16x8 bf = *(const bf16x8*)(brow + ks * 32);
      cq = __builtin_amdgcn_mfma_f32_16x16x32_bf16(aq[ks], bf, cq, 0, 0, 0);
      ck = __builtin_amdgcn_mfma_f32_16x16x32_bf16(ak[ks], bf, ck, 0, 0, 0);
      cv = __builtin_amdgcn_mfma_f32_16x16x32_bf16(av[ks], bf, cv, 0, 0, 0);
    }
    int l = n0 + 16 * t + ln;
    us4 pk;
#pragma unroll
    for (int r = 0; r < 4; ++r) pk[r] = f2bf((cq[r] + bq[r]) * QSCALE);
    *(us4*)(qd + (size_t)l * C_ + o0) = pk;
#pragma unroll
    for (int r = 0; r < 4; ++r) pk[r] = f2bf(ck[r] + bk[r]);
    *(us4*)(kd + (size_t)l * C_ + o0) = pk;
#pragma unroll
    for (int r = 0; r < 4; ++r) vd[(size_t)(o0 + r) * L_ + l] = f2bf(cv[r] + bv[r]);
  }
}

// ---------------- Flash attention: 8-wave block, K+V LDS pipelined (R8 structure, verbatim) ----
// q,k: [b][l][c] bf16 (q pre-scaled, log2 domain); v: [b][c][l] bf16.
// Writes unnormalized O partials po[g][l][c] + (m,l) in log2 domain.
__global__ __launch_bounds__(512) void attn_kernel(
    const unsigned short* __restrict__ qt, const unsigned short* __restrict__ kt,
    const unsigned short* __restrict__ vt, unsigned short* __restrict__ po,
    float2* __restrict__ ml) {
  __shared__ __attribute__((aligned(16))) char Kl[2][16384];  // 32 keys x 512B, XOR (row&7)<<4
  __shared__ __attribute__((aligned(16))) char Vl[2][16384];  // 256 c x 64B,  XOR ((c>>1)&3)<<4

  // XCD-chunked: 32 consecutive idx per XCD -> 2 (b,s) groups, KV slice ~2MB L2-resident
  int idx = (blockIdx.x & 7) * 32 + (blockIdx.x >> 3);
  int g = idx >> 4;                      // 0..15 = b*4+s
  int qtile = idx & 15;
  int b = g >> 2, s = g & 3;
  int jbase = s * (L_ / KVS_);
  const int NIT = (L_ / KVS_) / 32;      // 32

  int tid = threadIdx.x;
  int lane = tid & 63, wid = tid >> 6;
  int lq = lane & 31;                    // q-col / key-row / c-row
  int lk = lane >> 5;
  int q0 = qtile * 256 + wid * 32;

  const unsigned short* qb_ = qt + (size_t)b * L_ * C_;
  const unsigned short* kb_ = kt + (size_t)b * L_ * C_;
  const unsigned short* vb_ = vt + (size_t)b * C_ * L_;

  // staging (512 thr): per-thread 2 chunks of K (16KB) + 2 of V (16KB); source pre-swizzled
  auto stage = [&](int j0, int bs) {
#pragma unroll
    for (int r = 0; r < 2; ++r) {
      int addr = r * 8192 + tid * 16;
      int row = addr >> 9, colb = addr & 511;
      async_copy16((const char*)kb_ + (size_t)(j0 + row) * 512 + (colb ^ ((row & 7) << 4)),
                   Kl[bs] + addr);
    }
#pragma unroll
    for (int r = 0; r < 2; ++r) {
      int addr = r * 8192 + tid * 16;
      int c = addr >> 6, colb = addr & 63;
      async_copy16((const char*)vb_ + (size_t)c * (L_ * 2) + (size_t)j0 * 2 +
                       (colb ^ (((c >> 1) & 3) << 4)),
                   Vl[bs] + addr);
    }
  };

  // Q B-fragments: qf[kc] = Q[q0+lq][kc*16 + lk*8 .. +7]
  bf16x8 qf[16];
  const unsigned short* qrow = qb_ + (size_t)(q0 + lq) * C_ + lk * 8;
#pragma unroll
  for (int kc = 0; kc < 16; ++kc) qf[kc] = *(const bf16x8*)(qrow + kc * 16);

  stage(jbase, 0);
  stage(jbase + 32, 1);

  f32x16 oacc[8];
#pragma unroll
  for (int ct = 0; ct < 8; ++ct)
#pragma unroll
    for (int i = 0; i < 16; ++i) oacc[ct][i] = 0.f;

  float m_run = -3e38f, l_run = 0.f;     // log2 domain
  const int kswz = (lq & 7) << 4;
  const int vswz = ((lq >> 1) & 3) << 4;

#pragma unroll 1
  for (int jt = 0; jt < NIT; ++jt) {
    const char* Kb = Kl[jt & 1];
    const char* Vb = Vl[jt & 1];

    // tile jt landed (tile jt+1's 8 loads stay in flight)
    asm volatile("s_waitcnt vmcnt(8)" ::: "memory");
    __builtin_amdgcn_sched_barrier(0);
    __builtin_amdgcn_s_barrier();
    __builtin_amdgcn_sched_barrier(0);

    // ---- QK: S^T = K · Q^T (2 parallel chains); S already in log2 units ----
    f32x16 sa, sb;
#pragma unroll
    for (int i = 0; i < 16; ++i) { sa[i] = 0.f; sb[i] = 0.f; }
    __builtin_amdgcn_s_setprio(1);
#pragma unroll
    for (int kc = 0; kc < 16; kc += 2) {
      bf16x8 kf0 = *(const bf16x8*)(Kb + lq * 512 + ((kc * 32 + lk * 16) ^ kswz));
      sa = __builtin_amdgcn_mfma_f32_32x32x16_bf16(kf0, qf[kc], sa, 0, 0, 0);
      bf16x8 kf1 = *(const bf16x8*)(Kb + lq * 512 + (((kc + 1) * 32 + lk * 16) ^ kswz));
      sb = __builtin_amdgcn_mfma_f32_32x32x16_bf16(kf1, qf[kc + 1], sb, 0, 0, 0);
    }
    __builtin_amdgcn_s_setprio(0);
    f32x16 sacc = sa + sb;

    // ---- online softmax, in-register, log2 domain ----
    float pm = sacc[0];
#pragma unroll
    for (int i = 1; i < 16; ++i) pm = fmaxf(pm, sacc[i]);
    pm = fmaxf(pm, __shfl_xor(pm, 32));
    if (__any(pm > m_run + 8.0f)) {      // defer-max (T13)
      float mn = fmaxf(m_run, pm);
      float al = exp2f(m_run - mn);
      l_run *= al;
#pragma unroll
      for (int ct = 0; ct < 8; ++ct)
#pragma unroll
        for (int i = 0; i < 16; ++i) oacc[ct][i] *= al;
      m_run = mn;
    }
    float p[16];
    float ls = 0.f;
#pragma unroll
    for (int i = 0; i < 16; ++i) {
      p[i] = exp2f(sacc[i] - m_run);
      ls += p[i];
    }
    ls += __shfl_xor(ls, 32);
    l_run += ls;

    // ---- pack P -> bf16 B-frags via cvt_pk + permlane32_swap (T12) ----
    unsigned w[8];
#pragma unroll
    for (int i = 0; i < 8; ++i)
      asm("v_cvt_pk_bf16_f32 %0, %1, %2" : "=v"(w[i]) : "v"(p[2 * i]), "v"(p[2 * i + 1]));
    asm volatile("v_permlane32_swap_b32 %0, %1" : "+v"(w[0]), "+v"(w[2]));
    asm volatile("v_permlane32_swap_b32 %0, %1" : "+v"(w[1]), "+v"(w[3]));
    asm volatile("v_permlane32_swap_b32 %0, %1" : "+v"(w[4]), "+v"(w[6]));
    asm volatile("v_permlane32_swap_b32 %0, %1" : "+v"(w[5]), "+v"(w[7]));
    u32x4 t1 = {w[0], w[1], w[2], w[3]};
    u32x4 t2 = {w[4], w[5], w[6], w[7]};
    bf16x8 pb1 = __builtin_bit_cast(bf16x8, t1);
    bf16x8 pb2 = __builtin_bit_cast(bf16x8, t2);

    // ---- PV: O^T += V^T · P^T, V from LDS ----
    __builtin_amdgcn_s_setprio(1);
#pragma unroll
    for (int ct = 0; ct < 8; ++ct) {
      int vr = ct * 32 + lq;
      bf16x8 av0 = *(const bf16x8*)(Vb + vr * 64 + ((lk * 16) ^ vswz));
      oacc[ct] = __builtin_amdgcn_mfma_f32_32x32x16_bf16(av0, pb1, oacc[ct], 0, 0, 0);
      bf16x8 av1 = *(const bf16x8*)(Vb + vr * 64 + ((32 + lk * 16) ^ vswz));
      oacc[ct] = __builtin_amdgcn_mfma_f32_32x32x16_bf16(av1, pb2, oacc[ct], 0, 0, 0);
    }
    __builtin_amdgcn_s_setprio(0);

    __builtin_amdgcn_sched_barrier(0);
    __builtin_amdgcn_s_barrier();        // all reads of buf jt&1 done
    __builtin_amdgcn_sched_barrier(0);
    stage(jbase + ((jt + 2) & (NIT - 1)) * 32, jt & 1);  // wrap keeps vmcnt uniform
  }

  asm volatile("s_waitcnt vmcnt(0)" ::: "memory");  // drain wrap staging

  // ---- epilogue: unnormalized O partial + (m,l) (log2 domain) ----
  unsigned short* pob = po + ((size_t)g * L_ + q0 + lq) * C_;
#pragma unroll
  for (int ct = 0; ct < 8; ++ct) {
#pragma unroll
    for (int e = 0; e < 4; ++e) {
      us4 pk;
#pragma unroll
      for (int r = 0; r < 4; ++r) pk[r] = f2bf(oacc[ct][4 * e + r]);
      *(us4*)(pob + ct * 32 + 8 * e + 4 * lk) = pk;
    }
  }
  if (lane < 32)
    ml[(size_t)g * L_ + q0 + lq] = make_float2(m_run, l_run);
}

// ---------------- combine partials -> ot [b][l][c] bf16 (log2 domain m); us8-wide ----------------
__global__ __launch_bounds__(256) void combine_kernel(const unsigned short* __restrict__ po,
                                                      const float2* __restrict__ ml,
                                                      unsigned short* __restrict__ ot) {
  int tid = threadIdx.x;
  int row = blockIdx.x * 8 + (tid >> 5);   // b*L + l ; 8 rows/block, 32 lanes/row
  int b = row >> 12;
  int l = row & (L_ - 1);
  int lane = tid & 31;
  float2 mv[KVS_];
  float M = -3e38f;
#pragma unroll
  for (int s = 0; s < KVS_; ++s) {
    mv[s] = ml[(size_t)(b * KVS_ + s) * L_ + l];
    M = fmaxf(M, mv[s].x);
  }
  float acc[8] = {0.f, 0.f, 0.f, 0.f, 0.f, 0.f, 0.f, 0.f};
  float denom = 0.f;
#pragma unroll
  for (int s = 0; s < KVS_; ++s) {
    float w = exp2f(mv[s].x - M);
    denom += w * mv[s].y;
    us8 o = *(const us8*)(po + ((size_t)(b * KVS_ + s) * L_ + l) * C_ + lane * 8);
#pragma unroll
    for (int j = 0; j < 8; ++j) acc[j] += w * bf2f(o[j]);
  }
  float inv = 1.f / denom;
  us8 o;
#pragma unroll
  for (int j = 0; j < 8; ++j) o[j] = f2bf(acc[j] * inv);
  *(us8*)(ot + (size_t)row * C_ + lane * 8) = o;
}

// ---------------- proj GEMM + bias + residual (fp32 out) ----------------
__global__ __launch_bounds__(256) void proj_kernel(
    const unsigned short* __restrict__ wp, const float* __restrict__ pbias,
    const unsigned short* __restrict__ ot, const float* __restrict__ x,
    float* __restrict__ out) {
  int id = blockIdx.x;
  int nt = id & 63, mt = (id >> 6) & 3, b = id >> 8;
  int lane = threadIdx.x & 63, wid = threadIdx.x >> 6;
  int ln = lane & 15, lq = lane >> 4;
  int m0 = mt * 64 + wid * 16;
  int n0 = nt * 64;
  const unsigned short* ob = ot + (size_t)b * L_ * C_;
  bf16x8 a[8];
  const unsigned short* arow = wp + (m0 + ln) * C_ + lq * 8;
#pragma unroll
  for (int ks = 0; ks < 8; ++ks) a[ks] = *(const bf16x8*)(arow + ks * 32);
  f32x4 acc[4];
#pragma unroll
  for (int t = 0; t < 4; ++t) {
    f32x4 c = {0.f, 0.f, 0.f, 0.f};
    const unsigned short* brow = ob + (size_t)(n0 + 16 * t + ln) * C_ + lq * 8;
#pragma unroll
    for (int ks = 0; ks < 8; ++ks) {
      bf16x8 bf = *(const bf16x8*)(brow + ks * 32);
      c = __builtin_amdgcn_mfma_f32_16x16x32_bf16(a[ks], bf, c, 0, 0, 0);
    }
    acc[t] = c;
  }
  int o0 = m0 + lq * 4;
#pragma unroll
  for (int r = 0; r < 4; ++r) {
    float bvr = pbias[o0 + r];
    const float* xrow = x + ((size_t)b * C_ + o0 + r) * L_;
    float* orow = out + ((size_t)b * C_ + o0 + r) * L_;
#pragma unroll
    for (int t = 0; t < 4; ++t) {
      int l = n0 + 16 * t + ln;
      orow[l] = xrow[l] + acc[t][r] + bvr;
    }
  }
}

extern "C" void kernel_launch(void* const* d_in, const int* in_sizes, int n_in,
                              void* d_out, int out_size, void* d_ws, size_t ws_size,
                              hipStream_t stream) {
  const float* x   = (const float*)d_in[0];
  const float* gnw = (const float*)d_in[1];
  const float* gnb = (const float*)d_in[2];
  const float* qw  = (const float*)d_in[3];
  const float* qb  = (const float*)d_in[4];
  const float* kw  = (const float*)d_in[5];
  const float* kb  = (const float*)d_in[6];
  const float* vw  = (const float*)d_in[7];
  const float* vb  = (const float*)d_in[8];
  const float* pw  = (const float*)d_in[9];
  const float* pb  = (const float*)d_in[10];
  float* out = (float*)d_out;

  unsigned short* ws = (unsigned short*)d_ws;
  const size_t SZ = (size_t)B_ * L_ * C_;
  unsigned short* xn_t = ws;            // [b][l][c] bf16
  unsigned short* qt   = xn_t + SZ;     // [b][l][c] (pre-scaled, log2 domain)
  unsigned short* kt   = qt + SZ;       // [b][l][c]
  unsigned short* vt   = kt + SZ;       // [b][c][l]
  unsigned short* ot   = vt + SZ;       // [b][l][c]
  unsigned short* wb   = ot + SZ;       // 4 x [C][C] bf16 (q,k,v,p)
  unsigned short* po   = wb + 4 * C_ * C_;                   // [B*KVS][L][C]
  float2* ml = (float2*)(po + (size_t)KVS_ * SZ);            // [B*KVS][L]

  gn_wcvt_kernel<<<384, 256, 0, stream>>>(x, gnw, gnb, xn_t, qw, kw, vw, pw, wb);
  qkv_gemm_kernel<<<1024, 256, 0, stream>>>(wb, wb + C_ * C_, wb + 2 * C_ * C_,
                                            qb, kb, vb, xn_t, qt, kt, vt);
  attn_kernel<<<256, 512, 0, stream>>>(qt, kt, vt, po, ml);
  combine_kernel<<<B_ * L_ / 8, 256, 0, stream>>>(po, ml, ot);
  proj_kernel<<<1024, 256, 0, stream>>>(wb + 3 * C_ * C_, pb, ot, x, out);
}